// Round 8
// baseline (5858.148 us; speedup 1.0000x reference)
//
#include <hip/hip_runtime.h>
#include <hip/hip_bf16.h>

// ---------------------------------------------------------------------------
// PointNet++ encoder (4 SA stages) for MI355X.
// Stage pipeline: FPS -> gather new_xyz -> ball query -> fused group+MLP+maxpool.
// FPS / ball-query distance math matches numpy per-op IEEE semantics exactly
// (argmax selection must be exact; xyz output is raw copies).
// Stage-1 FPS: Morton spatial sort + WAVE-uniform conservative skip (scalar
// branch). Skips are provably exact (margins >> fp32 error; min-dists are
// monotone decreasing so cached wave winners/bounds stay valid).
// ---------------------------------------------------------------------------

#define B_SZ 4

typedef float v2f __attribute__((ext_vector_type(2)));
typedef unsigned long long u64;

// Packed-FP32 helpers (VOP3P). Each half is a plain IEEE f32 op, so results
// are bitwise identical to scalar v_add_f32/v_mul_f32.
__device__ __forceinline__ v2f pk_add(v2f a, v2f b) {
  v2f d;
  asm("v_pk_add_f32 %0, %1, %2" : "=v"(d) : "v"(a), "v"(b));
  return d;
}
__device__ __forceinline__ v2f pk_mul(v2f a, v2f b) {
  v2f d;
  asm("v_pk_mul_f32 %0, %1, %2" : "=v"(d) : "v"(a), "v"(b));
  return d;
}

template <int CTRL>
__device__ __forceinline__ u64 dpp_u64(u64 v) {
  int lo = (int)(unsigned)v;
  int hi = (int)(unsigned)(v >> 32);
  int nlo = __builtin_amdgcn_update_dpp(lo, lo, CTRL, 0xF, 0xF, false);
  int nhi = __builtin_amdgcn_update_dpp(hi, hi, CTRL, 0xF, 0xF, false);
  return ((u64)(unsigned)nhi << 32) | (unsigned)nlo;
}

// Full-wave (64-lane) max reduce on VALU pipe; result valid in lane 63.
__device__ __forceinline__ u64 wave_max_u64(u64 P) {
  u64 o;
  o = dpp_u64<0x111>(P); P = o > P ? o : P;  // row_shr:1
  o = dpp_u64<0x112>(P); P = o > P ? o : P;  // row_shr:2
  o = dpp_u64<0x114>(P); P = o > P ? o : P;  // row_shr:4
  o = dpp_u64<0x118>(P); P = o > P ? o : P;  // row_shr:8
  o = dpp_u64<0x142>(P); P = o > P ? o : P;  // row_bcast15
  o = dpp_u64<0x143>(P); P = o > P ? o : P;  // row_bcast31
  return P;
}

// 9-bit Morton code from 3-bit cell coords (phase-A only).
__device__ __forceinline__ int morton3(int x, int y, int z) {
  int m = 0;
#pragma unroll
  for (int b = 0; b < 3; ++b)
    m |= (((x >> b) & 1) << (3 * b + 2)) | (((y >> b) & 1) << (3 * b + 1)) |
         (((z >> b) & 1) << (3 * b + 0));
  return m;
}

// ---------------- stage-1 FPS: Morton sort + wave-uniform skip -------------
template <int N, int NPOINT, int T>
__global__ __launch_bounds__(T, 2) void fps_bucket_kernel(
    const float* __restrict__ xyz, int* __restrict__ fidx,
    float* __restrict__ gsx, float* __restrict__ gsy,
    float* __restrict__ gsz, int* __restrict__ gsi) {
#pragma clang fp contract(off)
  constexpr int PT = N / T;  // 32 points per thread
  constexpr int NP2 = PT / 2;
  constexpr int NW = T / 64;
  constexpr int NB = 512;  // 8x8x8 bins
  static_assert(T == NB, "one bin per thread");
  const int b = blockIdx.x;
  const int t = threadIdx.x;
  const int lane = t & 63;
  const int wv = t >> 6;
  const float* base = xyz + (size_t)b * N * 3;
  float* bsx = gsx + (size_t)b * N;
  float* bsy = gsy + (size_t)b * N;
  float* bsz = gsz + (size_t)b * N;
  int* bsi = gsi + (size_t)b * N;

  __shared__ int s_hist[NB];
  __shared__ int s_scan[NB];
  __shared__ float s_red[6][NW];
  __shared__ __align__(16) u64 s_key[2][NW];

  // ---- A1: bounding box ----
  float mnx = 1e30f, mny = 1e30f, mnz = 1e30f;
  float mxx = -1e30f, mxy = -1e30f, mxz = -1e30f;
  for (int k = 0; k < PT; ++k) {
    int i = t + k * T;
    float x = base[i * 3 + 0], y = base[i * 3 + 1], z = base[i * 3 + 2];
    mnx = fminf(mnx, x); mny = fminf(mny, y); mnz = fminf(mnz, z);
    mxx = fmaxf(mxx, x); mxy = fmaxf(mxy, y); mxz = fmaxf(mxz, z);
  }
#pragma unroll
  for (int off = 1; off < 64; off <<= 1) {
    mnx = fminf(mnx, __shfl_xor(mnx, off));
    mny = fminf(mny, __shfl_xor(mny, off));
    mnz = fminf(mnz, __shfl_xor(mnz, off));
    mxx = fmaxf(mxx, __shfl_xor(mxx, off));
    mxy = fmaxf(mxy, __shfl_xor(mxy, off));
    mxz = fmaxf(mxz, __shfl_xor(mxz, off));
  }
  if (lane == 0) {
    s_red[0][wv] = mnx; s_red[1][wv] = mny; s_red[2][wv] = mnz;
    s_red[3][wv] = mxx; s_red[4][wv] = mxy; s_red[5][wv] = mxz;
  }
  s_hist[t] = 0;
  __syncthreads();
  mnx = s_red[0][0]; mny = s_red[1][0]; mnz = s_red[2][0];
  mxx = s_red[3][0]; mxy = s_red[4][0]; mxz = s_red[5][0];
#pragma unroll
  for (int w = 1; w < NW; ++w) {
    mnx = fminf(mnx, s_red[0][w]); mny = fminf(mny, s_red[1][w]);
    mnz = fminf(mnz, s_red[2][w]);
    mxx = fmaxf(mxx, s_red[3][w]); mxy = fmaxf(mxy, s_red[4][w]);
    mxz = fmaxf(mxz, s_red[5][w]);
  }
  const float fx = 8.0f / (mxx - mnx + 1e-5f);
  const float fy = 8.0f / (mxy - mny + 1e-5f);
  const float fz = 8.0f / (mxz - mnz + 1e-5f);

  // ---- A2: histogram over Morton bins ----
  for (int k = 0; k < PT; ++k) {
    int i = t + k * T;
    float x = base[i * 3 + 0], y = base[i * 3 + 1], z = base[i * 3 + 2];
    int cx = min(7, max(0, (int)((x - mnx) * fx)));
    int cy = min(7, max(0, (int)((y - mny) * fy)));
    int cz = min(7, max(0, (int)((z - mnz) * fz)));
    atomicAdd(&s_hist[morton3(cx, cy, cz)], 1);
  }
  __syncthreads();

  // ---- A3: block exclusive scan over 512 bins ----
  s_scan[t] = s_hist[t];
  __syncthreads();
  for (int off = 1; off < NB; off <<= 1) {
    int v = (t >= off) ? s_scan[t - off] : 0;
    __syncthreads();
    s_scan[t] += v;
    __syncthreads();
  }
  s_hist[t] = s_scan[t] - s_hist[t];
  __syncthreads();

  // ---- A4: scatter (Morton spatial sort). Within-cell order nondeterminism
  // is harmless: ties break on ORIGINAL index via the packed key. ----
  for (int k = 0; k < PT; ++k) {
    int i = t + k * T;
    float x = base[i * 3 + 0], y = base[i * 3 + 1], z = base[i * 3 + 2];
    int cx = min(7, max(0, (int)((x - mnx) * fx)));
    int cy = min(7, max(0, (int)((y - mny) * fy)));
    int cz = min(7, max(0, (int)((z - mnz) * fz)));
    int pos = atomicAdd(&s_hist[morton3(cx, cy, cz)], 1);
    bsx[pos] = x; bsy[pos] = y; bsz[pos] = z; bsi[pos] = i;
  }
  __threadfence();
  __syncthreads();

  // ---- A5: load my 32 contiguous sorted points ----
  v2f px[NP2], py[NP2], pz[NP2], dv[NP2];
  unsigned lo[PT];  // N - original_index (compile-time indexed only)
#pragma unroll
  for (int k = 0; k < PT; ++k) {
    int pos = t * PT + k;
    float x = bsx[pos], y = bsy[pos], z = bsz[pos];
    px[k / 2][k & 1] = x; py[k / 2][k & 1] = y; pz[k / 2][k & 1] = z;
    dv[k / 2][k & 1] = 1e10f;
    lo[k] = (unsigned)(N - bsi[pos]);
  }

  // ---- A6: WAVE bounding sphere (2048 contiguous Morton points) ----
  float wmnx = 1e30f, wmny = 1e30f, wmnz = 1e30f;
  float wmxx = -1e30f, wmxy = -1e30f, wmxz = -1e30f;
#pragma unroll
  for (int k = 0; k < PT; ++k) {
    float x = px[k / 2][k & 1], y = py[k / 2][k & 1], z = pz[k / 2][k & 1];
    wmnx = fminf(wmnx, x); wmny = fminf(wmny, y); wmnz = fminf(wmnz, z);
    wmxx = fmaxf(wmxx, x); wmxy = fmaxf(wmxy, y); wmxz = fmaxf(wmxz, z);
  }
#pragma unroll
  for (int off = 1; off < 64; off <<= 1) {
    wmnx = fminf(wmnx, __shfl_xor(wmnx, off));
    wmny = fminf(wmny, __shfl_xor(wmny, off));
    wmnz = fminf(wmnz, __shfl_xor(wmnz, off));
    wmxx = fmaxf(wmxx, __shfl_xor(wmxx, off));
    wmxy = fmaxf(wmxy, __shfl_xor(wmxy, off));
    wmxz = fmaxf(wmxz, __shfl_xor(wmxz, off));
  }
  const float wcx = 0.5f * (wmnx + wmxx);
  const float wcy = 0.5f * (wmny + wmxy);
  const float wcz = 0.5f * (wmnz + wmxz);
  float wr2 = 0.f;
#pragma unroll
  for (int k = 0; k < PT; ++k) {
    float dx = px[k / 2][k & 1] - wcx, dy = py[k / 2][k & 1] - wcy,
          dz = pz[k / 2][k & 1] - wcz;
    wr2 = fmaxf(wr2, dx * dx + dy * dy + dz * dz);
  }
#pragma unroll
  for (int off = 1; off < 64; off <<= 1) wr2 = fmaxf(wr2, __shfl_xor(wr2, off));
  const float wcrad = sqrtf(wr2) * 1.0001f + 1e-7f;

  // cached post-reduce wave winner (lane 63's value is the meaningful one)
  u64 Pred = 0;
  float wcm = 1e30f;  // wave cmax upper bound: max dv over wave (monotone ok)

  float cenx = base[0], ceny = base[1], cenz = base[2];
  int far = 0;
  int p = 0;

  for (int it = 0; it < NPOINT; ++it) {
    if (t == 0) fidx[b * NPOINT + it] = far;

    // wave-uniform conservative skip (identical inputs in every lane)
    float ddx = wcx - cenx, ddy = wcy - ceny, ddz = wcz - cenz;
    float dc = sqrtf(ddx * ddx + ddy * ddy + ddz * ddz);
    float lb = dc - wcrad;
    int sk = (lb > 0.f) && (lb * lb * 0.9999f >= wcm * 1.0001f);
    if (__builtin_amdgcn_readfirstlane(sk) == 0) {
      // update all 32 points (exact reference op order)
      const float nx = -cenx, ny = -ceny, nz = -cenz;
      const v2f c2x = {nx, nx}, c2y = {ny, ny}, c2z = {nz, nz};
      float mx0 = -1.f, mx1 = -1.f, mx2 = -1.f, mx3 = -1.f;
#pragma unroll
      for (int j = 0; j < NP2; ++j) {
        v2f dx = pk_add(px[j], c2x);
        v2f dy = pk_add(py[j], c2y);
        v2f dz = pk_add(pz[j], c2z);
        v2f xx = pk_mul(dx, dx);
        v2f yy = pk_mul(dy, dy);
        v2f zz = pk_mul(dz, dz);
        v2f s = pk_add(xx, yy);
        v2f d = pk_add(s, zz);
        float nd0 = fminf(dv[j][0], d[0]);
        float nd1 = fminf(dv[j][1], d[1]);
        dv[j][0] = nd0; dv[j][1] = nd1;
        float m2 = fmaxf(nd0, nd1);
        if ((j & 3) == 0) mx0 = fmaxf(m2, mx0);
        if ((j & 3) == 1) mx1 = fmaxf(m2, mx1);
        if ((j & 3) == 2) mx2 = fmaxf(m2, mx2);
        if ((j & 3) == 3) mx3 = fmaxf(m2, mx3);
      }
      float m = fmaxf(fmaxf(mx0, mx1), fmaxf(mx2, mx3));
      // recover index: among dv[k]==m take LARGEST lo (= smallest orig idx)
      unsigned kl = 0;
#pragma unroll
      for (int j = 0; j < NP2; ++j) {
        kl = (dv[j][0] == m && lo[2 * j] > kl) ? lo[2 * j] : kl;
        kl = (dv[j][1] == m && lo[2 * j + 1] > kl) ? lo[2 * j + 1] : kl;
      }
      u64 P = ((u64)__float_as_uint(m) << 32) | kl;
      P = wave_max_u64(P);
      Pred = P;
      wcm = __uint_as_float(
          (unsigned)__builtin_amdgcn_readlane((int)(unsigned)(P >> 32), 63));
    }
    if (lane == 63) s_key[p][wv] = Pred;
    __syncthreads();
    u64 bb = s_key[p][0];
#pragma unroll
    for (int w = 1; w < NW; ++w) {
      u64 v = s_key[p][w];
      bb = v > bb ? v : bb;
    }
    far = N - (int)(unsigned)(bb & 0xffffffffull);
    cenx = base[far * 3 + 0];
    ceny = base[far * 3 + 1];
    cenz = base[far * 3 + 2];
    p ^= 1;
  }
}

// ------------------------ brute FPS (stages 2-4) ---------------------------
template <int N, int NPOINT, int T, bool XYZ_IN_LDS>
__global__ __launch_bounds__(T, (T / 256 > 0) ? T / 256 : 1) void fps_kernel(
    const float* __restrict__ xyz, int* __restrict__ fidx) {
#pragma clang fp contract(off)
  constexpr int PT = N / T;
  static_assert(PT % 2 == 0, "PT even");
  constexpr int NP2 = PT / 2;
  constexpr int NW = T / 64;
  constexpr int NACC = (NP2 >= 4) ? 4 : NP2;
  constexpr int LN = XYZ_IN_LDS ? N : 1;
  const int b = blockIdx.x;
  const int t = threadIdx.x;
  const int lane = t & 63;
  const int wv = t >> 6;
  const float* base = xyz + (size_t)b * N * 3;

  v2f px[NP2], py[NP2], pz[NP2], dv[NP2];
  __shared__ __align__(16) u64 s_pack[2][NW];
  __shared__ float s_x[LN], s_y[LN], s_z[LN];

#pragma unroll
  for (int j = 0; j < NP2; ++j) {
    int i0 = t + (2 * j) * T;
    int i1 = t + (2 * j + 1) * T;
    px[j][0] = base[i0 * 3 + 0]; py[j][0] = base[i0 * 3 + 1];
    pz[j][0] = base[i0 * 3 + 2];
    px[j][1] = base[i1 * 3 + 0]; py[j][1] = base[i1 * 3 + 1];
    pz[j][1] = base[i1 * 3 + 2];
    dv[j][0] = 1e10f; dv[j][1] = 1e10f;
    if constexpr (XYZ_IN_LDS) {
      s_x[i0] = px[j][0]; s_y[i0] = py[j][0]; s_z[i0] = pz[j][0];
      s_x[i1] = px[j][1]; s_y[i1] = py[j][1]; s_z[i1] = pz[j][1];
    }
  }
  __syncthreads();

  int far = 0;
  int p = 0;
  for (int it = 0; it < NPOINT; ++it) {
    if (t == 0) fidx[b * NPOINT + it] = far;
    float cx, cy, cz;
    if constexpr (XYZ_IN_LDS) {
      cx = s_x[far]; cy = s_y[far]; cz = s_z[far];
    } else {
      cx = base[far * 3 + 0]; cy = base[far * 3 + 1]; cz = base[far * 3 + 2];
    }
    const float nx = -cx, ny = -cy, nz = -cz;
    const v2f c2x = {nx, nx}, c2y = {ny, ny}, c2z = {nz, nz};

    float mx[NACC];
#pragma unroll
    for (int q = 0; q < NACC; ++q) mx[q] = -1.0f;

#pragma unroll
    for (int j = 0; j < NP2; ++j) {
      v2f dx = pk_add(px[j], c2x);
      v2f dy = pk_add(py[j], c2y);
      v2f dz = pk_add(pz[j], c2z);
      v2f xx = pk_mul(dx, dx);
      v2f yy = pk_mul(dy, dy);
      v2f zz = pk_mul(dz, dz);
      v2f s = pk_add(xx, yy);
      v2f d = pk_add(s, zz);
      float nd0 = fminf(dv[j][0], d[0]);
      float nd1 = fminf(dv[j][1], d[1]);
      dv[j][0] = nd0; dv[j][1] = nd1;
      const int q = j % NACC;
      mx[q] = fmaxf(fmaxf(nd0, nd1), mx[q]);
    }
    float m = mx[0];
#pragma unroll
    for (int q = 1; q < NACC; ++q) m = fmaxf(m, mx[q]);

    int bk = 0;
#pragma unroll
    for (int j = NP2 - 1; j >= 0; --j) {
      if (dv[j][1] == m) bk = 2 * j + 1;
      if (dv[j][0] == m) bk = 2 * j;
    }

    int idx = t + bk * T;
    u64 P = ((u64)__float_as_uint(m) << 32) | (unsigned)(N - idx);
    P = wave_max_u64(P);
    if (lane == 63) s_pack[p][wv] = P;
    __syncthreads();
    u64 bbp = s_pack[p][0];
#pragma unroll
    for (int w = 1; w < NW; ++w) {
      u64 v = s_pack[p][w];
      bbp = v > bbp ? v : bbp;
    }
    far = N - (int)(unsigned)(bbp & 0xffffffffull);
    p ^= 1;
  }
}

// --------------------------- gather new_xyz --------------------------------
__global__ void gather_xyz_kernel(const float* __restrict__ xyz,
                                  const int* __restrict__ fidx,
                                  float* __restrict__ out, int N, int S) {
  int s = blockIdx.x * blockDim.x + threadIdx.x;
  int b = blockIdx.y;
  if (s < S) {
    int i = fidx[b * S + s];
    out[((size_t)(b * S + s)) * 3 + 0] = xyz[((size_t)(b * N + i)) * 3 + 0];
    out[((size_t)(b * S + s)) * 3 + 1] = xyz[((size_t)(b * N + i)) * 3 + 1];
    out[((size_t)(b * S + s)) * 3 + 2] = xyz[((size_t)(b * N + i)) * 3 + 2];
  }
}

// ----------------------------- ball query ----------------------------------
template <int N, int NS>
__global__ __launch_bounds__(256) void ball_query_kernel(
    const float* __restrict__ xyz, const float* __restrict__ new_xyz,
    int* __restrict__ nidx, int S, float r2) {
#pragma clang fp contract(off)
  const int wv = threadIdx.x >> 6;
  const int lane = threadIdx.x & 63;
  const int b = blockIdx.y;
  const int s = blockIdx.x * 4 + wv;
  __shared__ int s_idx[4][NS];
  const float* base = xyz + (size_t)b * N * 3;

  float cx = new_xyz[((size_t)(b * S + s)) * 3 + 0];
  float cy = new_xyz[((size_t)(b * S + s)) * 3 + 1];
  float cz = new_xyz[((size_t)(b * S + s)) * 3 + 2];
  float sc = (cx * cx + cy * cy) + cz * cz;

  int found = 0;
  for (int i0 = 0; i0 < N && found < NS; i0 += 64) {
    int i = i0 + lane;
    float x = base[i * 3 + 0];
    float y = base[i * 3 + 1];
    float z = base[i * 3 + 2];
    float sx = (x * x + y * y) + z * z;
    float dt = (cx * x + cy * y) + cz * z;
    float d2 = (sc + sx) - 2.0f * dt;
    bool inb = d2 < r2;
    unsigned long long m = __ballot(inb);
    if (inb) {
      int pos = found + __popcll(m & ((1ull << lane) - 1));
      if (pos < NS) s_idx[wv][pos] = i;
    }
    found += __popcll(m);
  }
  __syncthreads();
  int fcnt = found < NS ? found : NS;
  int first = s_idx[wv][0];
  int* outp = nidx + ((size_t)(b * S + s)) * NS;
  for (int j = lane; j < NS; j += 64) outp[j] = (j < fcnt) ? s_idx[wv][j] : first;
}

// --------------------------- fused group MLP -------------------------------
template <int R, int RG, int CG, int CMAXP, int CIN, int COUT>
__device__ __forceinline__ void mlp_layer(float* act, const float* __restrict__ w,
                                          const float* __restrict__ bias, int tid) {
  constexpr int RPT = R / RG;
  constexpr int CPT = COUT / CG;
  static_assert(RG * CG == 256, "thread grid");
  const int rg = tid / CG;
  const int cg = tid % CG;

  float acc[RPT][CPT];
#pragma unroll
  for (int rr = 0; rr < RPT; ++rr)
#pragma unroll
    for (int cc = 0; cc < CPT; ++cc) acc[rr][cc] = 0.f;

  constexpr int K4 = (CIN / 4) * 4;
  for (int k = 0; k < K4; k += 4) {
    float4 a[RPT];
#pragma unroll
    for (int rr = 0; rr < RPT; ++rr)
      a[rr] = *(const float4*)(&act[(rg * RPT + rr) * CMAXP + k]);
    float wvv[4][CPT];
#pragma unroll
    for (int kk = 0; kk < 4; ++kk)
#pragma unroll
      for (int cc = 0; cc < CPT; ++cc)
        wvv[kk][cc] = w[(size_t)(k + kk) * COUT + cg + cc * CG];
#pragma unroll
    for (int rr = 0; rr < RPT; ++rr) {
      float4 av = a[rr];
#pragma unroll
      for (int cc = 0; cc < CPT; ++cc) {
        acc[rr][cc] += av.x * wvv[0][cc];
        acc[rr][cc] += av.y * wvv[1][cc];
        acc[rr][cc] += av.z * wvv[2][cc];
        acc[rr][cc] += av.w * wvv[3][cc];
      }
    }
  }
#pragma unroll 1
  for (int k = K4; k < CIN; ++k) {
    float wvv[CPT];
#pragma unroll
    for (int cc = 0; cc < CPT; ++cc) wvv[cc] = w[(size_t)k * COUT + cg + cc * CG];
#pragma unroll
    for (int rr = 0; rr < RPT; ++rr) {
      float av = act[(rg * RPT + rr) * CMAXP + k];
#pragma unroll
      for (int cc = 0; cc < CPT; ++cc) acc[rr][cc] += av * wvv[cc];
    }
  }
  __syncthreads();
#pragma unroll
  for (int rr = 0; rr < RPT; ++rr)
#pragma unroll
    for (int cc = 0; cc < CPT; ++cc) {
      int co = cg + cc * CG;
      float v = acc[rr][cc] + bias[co];
      act[(rg * RPT + rr) * CMAXP + co] = fmaxf(v, 0.f);
    }
  __syncthreads();
}

template <int NS, int G, int CPREV, int CO0, int CO1, int CO2, int RG, int CG, int CMAXP>
__global__ __launch_bounds__(256) void group_mlp_kernel(
    const float* __restrict__ xyz, const float* __restrict__ new_xyz,
    const float* __restrict__ feats, const int* __restrict__ nidx,
    const float* __restrict__ w0, const float* __restrict__ b0,
    const float* __restrict__ w1, const float* __restrict__ b1,
    const float* __restrict__ w2, const float* __restrict__ b2,
    float* __restrict__ out, int N, int S, float radius) {
  constexpr int R = NS * G;
  constexpr int CIN = 3 + CPREV;
  __shared__ __align__(16) float act[R * CMAXP];
  const int tid = threadIdx.x;
  const int b = blockIdx.y;
  const int s0 = blockIdx.x * G;

  for (int i = tid; i < R * CIN; i += 256) {
    int row = i / CIN;
    int ch = i - row * CIN;
    int g = row / NS;
    int j = row - g * NS;
    int sidx = s0 + g;
    int n = nidx[((size_t)(b * S + sidx)) * NS + j];
    float v;
    if constexpr (CPREV == 0) {
      v = (xyz[((size_t)(b * N + n)) * 3 + ch] -
           new_xyz[((size_t)(b * S + sidx)) * 3 + ch]) /
          radius;
    } else {
      if (ch < 3) {
        v = (xyz[((size_t)(b * N + n)) * 3 + ch] -
             new_xyz[((size_t)(b * S + sidx)) * 3 + ch]) /
            radius;
      } else {
        v = feats[((size_t)(b * N + n)) * CPREV + (ch - 3)];
      }
    }
    act[row * CMAXP + ch] = v;
  }
  __syncthreads();

  mlp_layer<R, RG, CG, CMAXP, CIN, CO0>(act, w0, b0, tid);
  mlp_layer<R, RG, CG, CMAXP, CO0, CO1>(act, w1, b1, tid);
  mlp_layer<R, RG, CG, CMAXP, CO1, CO2>(act, w2, b2, tid);

  for (int i = tid; i < G * CO2; i += 256) {
    int g = i / CO2;
    int co = i - g * CO2;
    float m = act[(g * NS) * CMAXP + co];
    for (int j = 1; j < NS; ++j) m = fmaxf(m, act[(g * NS + j) * CMAXP + co]);
    out[((size_t)(b * S + s0 + g)) * CO2 + co] = m;
  }
}

// ---------------------------------------------------------------------------
extern "C" void kernel_launch(void* const* d_in, const int* in_sizes, int n_in,
                              void* d_out, int out_size, void* d_ws, size_t ws_size,
                              hipStream_t stream) {
  (void)in_sizes; (void)n_in; (void)out_size; (void)ws_size;
  const float* pc = (const float*)d_in[0];
  const float* W[4][3];
  const float* Bb[4][3];
  for (int s = 0; s < 4; ++s)
    for (int l = 0; l < 3; ++l) {
      W[s][l] = (const float*)d_in[1 + s * 6 + l * 2];
      Bb[s][l] = (const float*)d_in[2 + s * 6 + l * 2];
    }

  // workspace layout (bytes): fidx 32KB | nidx 2MB | xyzA 96KB | xyzB 96KB |
  // featA 4MB | featB 4MB. Stage-1 sort scratch (1MB) aliases featB (featB is
  // first written by stage-2 group_mlp, after stage-1 FPS has completed).
  char* wsp = (char*)d_ws;
  int* fidx = (int*)wsp;
  int* nidx = (int*)(wsp + (32 << 10));
  float* xyzA = (float*)(wsp + (32 << 10) + (2 << 20));
  float* xyzB = xyzA + B_SZ * 2048 * 3;
  float* featA = xyzB + B_SZ * 2048 * 3;
  float* featB = featA + B_SZ * 2048 * 128;
  float* gsx = featB;  // 4*16384 floats each
  float* gsy = gsx + B_SZ * 16384;
  float* gsz = gsy + B_SZ * 16384;
  int* gsi = (int*)(gsz + B_SZ * 16384);
  float* oxyz = (float*)d_out;           // [4,256,3]
  float* ofeat = oxyz + B_SZ * 256 * 3;  // [4,256,512]

  // ---------------- Stage 1: N=16384 -> S=2048, r=0.2, ns=64, 3->64->64->128
  hipLaunchKernelGGL((fps_bucket_kernel<16384, 2048, 512>), dim3(B_SZ), dim3(512), 0, stream,
                     pc, fidx, gsx, gsy, gsz, gsi);
  hipLaunchKernelGGL(gather_xyz_kernel, dim3(32, B_SZ), dim3(64), 0, stream,
                     pc, fidx, xyzA, 16384, 2048);
  hipLaunchKernelGGL((ball_query_kernel<16384, 64>), dim3(512, B_SZ), dim3(256), 0, stream,
                     pc, xyzA, nidx, 2048, (float)(0.2 * 0.2));
  hipLaunchKernelGGL((group_mlp_kernel<64, 1, 0, 64, 64, 128, 8, 32, 128>),
                     dim3(2048, B_SZ), dim3(256), 0, stream,
                     pc, xyzA, (const float*)nullptr, nidx,
                     W[0][0], Bb[0][0], W[0][1], Bb[0][1], W[0][2], Bb[0][2],
                     featA, 16384, 2048, 0.2f);

  // ---------------- Stage 2: N=2048 -> S=1024, r=0.4, ns=32, 131->128->128->256
  hipLaunchKernelGGL((fps_kernel<2048, 1024, 512, true>), dim3(B_SZ), dim3(512), 0, stream,
                     xyzA, fidx);
  hipLaunchKernelGGL(gather_xyz_kernel, dim3(16, B_SZ), dim3(64), 0, stream,
                     xyzA, fidx, xyzB, 2048, 1024);
  hipLaunchKernelGGL((ball_query_kernel<2048, 32>), dim3(256, B_SZ), dim3(256), 0, stream,
                     xyzA, xyzB, nidx, 1024, (float)(0.4 * 0.4));
  hipLaunchKernelGGL((group_mlp_kernel<32, 1, 128, 128, 128, 256, 4, 64, 256>),
                     dim3(1024, B_SZ), dim3(256), 0, stream,
                     xyzA, xyzB, featA, nidx,
                     W[1][0], Bb[1][0], W[1][1], Bb[1][1], W[1][2], Bb[1][2],
                     featB, 2048, 1024, 0.4f);

  // ---------------- Stage 3: N=1024 -> S=512, r=0.6, ns=16, 259->256->256->512
  hipLaunchKernelGGL((fps_kernel<1024, 512, 256, true>), dim3(B_SZ), dim3(256), 0, stream,
                     xyzB, fidx);
  hipLaunchKernelGGL(gather_xyz_kernel, dim3(8, B_SZ), dim3(64), 0, stream,
                     xyzB, fidx, xyzA, 1024, 512);
  hipLaunchKernelGGL((ball_query_kernel<1024, 16>), dim3(128, B_SZ), dim3(256), 0, stream,
                     xyzB, xyzA, nidx, 512, (float)(0.6 * 0.6));
  hipLaunchKernelGGL((group_mlp_kernel<16, 1, 256, 256, 256, 512, 2, 128, 512>),
                     dim3(512, B_SZ), dim3(256), 0, stream,
                     xyzB, xyzA, featB, nidx,
                     W[2][0], Bb[2][0], W[2][1], Bb[2][1], W[2][2], Bb[2][2],
                     featA, 1024, 512, 0.6f);

  // ---------------- Stage 4: N=512 -> S=256, r=1.2, ns=8, 515->512->512->512
  hipLaunchKernelGGL((fps_kernel<512, 256, 256, true>), dim3(B_SZ), dim3(256), 0, stream,
                     xyzA, fidx);
  hipLaunchKernelGGL(gather_xyz_kernel, dim3(4, B_SZ), dim3(64), 0, stream,
                     xyzA, fidx, oxyz, 512, 256);
  hipLaunchKernelGGL((ball_query_kernel<512, 8>), dim3(64, B_SZ), dim3(256), 0, stream,
                     xyzA, oxyz, nidx, 256, (float)(1.2 * 1.2));
  hipLaunchKernelGGL((group_mlp_kernel<8, 2, 512, 512, 512, 512, 2, 128, 516>),
                     dim3(128, B_SZ), dim3(256), 0, stream,
                     xyzA, oxyz, featA, nidx,
                     W[3][0], Bb[3][0], W[3][1], Bb[3][1], W[3][2], Bb[3][2],
                     ofeat, 512, 256, 1.2f);
}

// Round 9
// 5031.249 us; speedup vs baseline: 1.1644x; 1.1644x over previous
//
#include <hip/hip_runtime.h>
#include <hip/hip_bf16.h>

// ---------------------------------------------------------------------------
// PointNet++ encoder (4 SA stages) for MI355X.
// Stage pipeline: FPS -> gather new_xyz -> ball query -> fused group+MLP+maxpool.
// FPS / ball-query distance math matches numpy per-op IEEE semantics exactly
// (argmax selection must be exact; xyz output is raw copies).
// Stage-s MLP is fused with stage-(s+1) FPS (independent work): blocks 0-3 run
// the latency-critical FPS at raised wave priority, the rest run the MLP.
// ---------------------------------------------------------------------------

#define B_SZ 4

typedef float v2f __attribute__((ext_vector_type(2)));
typedef unsigned long long u64;

// Packed-FP32 helpers (VOP3P). Each half is a plain IEEE f32 op, so results
// are bitwise identical to scalar v_add_f32/v_mul_f32.
__device__ __forceinline__ v2f pk_add(v2f a, v2f b) {
  v2f d;
  asm("v_pk_add_f32 %0, %1, %2" : "=v"(d) : "v"(a), "v"(b));
  return d;
}
__device__ __forceinline__ v2f pk_mul(v2f a, v2f b) {
  v2f d;
  asm("v_pk_mul_f32 %0, %1, %2" : "=v"(d) : "v"(a), "v"(b));
  return d;
}

template <int CTRL>
__device__ __forceinline__ u64 dpp_u64(u64 v) {
  int lo = (int)(unsigned)v;
  int hi = (int)(unsigned)(v >> 32);
  int nlo = __builtin_amdgcn_update_dpp(lo, lo, CTRL, 0xF, 0xF, false);
  int nhi = __builtin_amdgcn_update_dpp(hi, hi, CTRL, 0xF, 0xF, false);
  return ((u64)(unsigned)nhi << 32) | (unsigned)nlo;
}

// Full-wave (64-lane) max reduce on VALU pipe; result valid in lane 63.
__device__ __forceinline__ u64 wave_max_u64(u64 P) {
  u64 o;
  o = dpp_u64<0x111>(P); P = o > P ? o : P;  // row_shr:1
  o = dpp_u64<0x112>(P); P = o > P ? o : P;  // row_shr:2
  o = dpp_u64<0x114>(P); P = o > P ? o : P;  // row_shr:4
  o = dpp_u64<0x118>(P); P = o > P ? o : P;  // row_shr:8
  o = dpp_u64<0x142>(P); P = o > P ? o : P;  // row_bcast15
  o = dpp_u64<0x143>(P); P = o > P ? o : P;  // row_bcast31
  return P;
}

// ---------------------- stage-1 FPS (global xyz) ---------------------------
// One block per batch; ONE barrier per iteration. Hot loop per point-pair:
// 8 pk ops (exact op order), 2 fmin, 1 v_max3. Index recovered by descending
// rescan for dv[k]==m (first occurrence = smallest index = jnp.argmax).
// Tail: packed u64 DPP reduce; then each wave SPECULATIVELY prefetches its
// own winner's coords from global (latency hides under straggler waves +
// barrier), winner coords distributed via LDS -> no serial global fetch.
template <int N, int NPOINT, int T>
__global__ __launch_bounds__(T, 2) void fps1_kernel(const float* __restrict__ xyz,
                                                    int* __restrict__ fidx) {
#pragma clang fp contract(off)
  constexpr int PT = N / T;
  static_assert(PT % 2 == 0, "PT even");
  constexpr int NP2 = PT / 2;
  constexpr int NW = T / 64;
  constexpr int NACC = (NP2 >= 4) ? 4 : NP2;
  const int b = blockIdx.x;
  const int t = threadIdx.x;
  const int lane = t & 63;
  const int wv = t >> 6;
  const float* base = xyz + (size_t)b * N * 3;

  v2f px[NP2], py[NP2], pz[NP2], dv[NP2];
  __shared__ __align__(16) u64 s_key[2][NW];
  __shared__ float s_cx[2][NW], s_cy[2][NW], s_cz[2][NW];

#pragma unroll
  for (int j = 0; j < NP2; ++j) {
    int i0 = t + (2 * j) * T;
    int i1 = t + (2 * j + 1) * T;
    px[j][0] = base[i0 * 3 + 0]; py[j][0] = base[i0 * 3 + 1];
    pz[j][0] = base[i0 * 3 + 2];
    px[j][1] = base[i1 * 3 + 0]; py[j][1] = base[i1 * 3 + 1];
    pz[j][1] = base[i1 * 3 + 2];
    dv[j][0] = 1e10f; dv[j][1] = 1e10f;
  }

  int far = 0;
  float cenx = base[0], ceny = base[1], cenz = base[2];
  int p = 0;
  for (int it = 0; it < NPOINT; ++it) {
    if (t == 0) fidx[b * NPOINT + it] = far;
    // (p - c) computed as p + (-c): bitwise identical to IEEE subtraction.
    const float nx = -cenx, ny = -ceny, nz = -cenz;
    const v2f c2x = {nx, nx}, c2y = {ny, ny}, c2z = {nz, nz};

    float mx[NACC];
#pragma unroll
    for (int q = 0; q < NACC; ++q) mx[q] = -1.0f;

#pragma unroll
    for (int j = 0; j < NP2; ++j) {
      v2f dx = pk_add(px[j], c2x);
      v2f dy = pk_add(py[j], c2y);
      v2f dz = pk_add(pz[j], c2z);
      v2f xx = pk_mul(dx, dx);
      v2f yy = pk_mul(dy, dy);
      v2f zz = pk_mul(dz, dz);
      v2f s = pk_add(xx, yy);
      v2f d = pk_add(s, zz);
      float nd0 = fminf(dv[j][0], d[0]);
      float nd1 = fminf(dv[j][1], d[1]);
      dv[j][0] = nd0; dv[j][1] = nd1;
      const int q = j % NACC;
      mx[q] = fmaxf(fmaxf(nd0, nd1), mx[q]);  // -> v_max3_f32
    }
    float m = mx[0];
#pragma unroll
    for (int q = 1; q < NACC; ++q) m = fmaxf(m, mx[q]);

    // rescan for FIRST k with dv[k]==m (descending overwrite -> smallest idx)
    int bk = 0;
#pragma unroll
    for (int j = NP2 - 1; j >= 0; --j) {
      if (dv[j][1] == m) bk = 2 * j + 1;
      if (dv[j][0] == m) bk = 2 * j;
    }

    int idx = t + bk * T;
    u64 P = ((u64)__float_as_uint(m) << 32) | (unsigned)(N - idx);
    P = wave_max_u64(P);

    // speculative per-wave winner coord prefetch (wave-uniform address)
    int wf = N - __builtin_amdgcn_readlane((int)(unsigned)(P & 0xffffffffull), 63);
    float wx = base[wf * 3 + 0];
    float wy = base[wf * 3 + 1];
    float wz = base[wf * 3 + 2];
    if (lane == 63) s_key[p][wv] = P;
    if (lane == 0) { s_cx[p][wv] = wx; s_cy[p][wv] = wy; s_cz[p][wv] = wz; }
    __syncthreads();
    u64 bb = s_key[p][0];
    int mw = 0;
#pragma unroll
    for (int w = 1; w < NW; ++w) {
      u64 v = s_key[p][w];
      if (v > bb) { bb = v; mw = w; }
    }
    far = N - (int)(unsigned)(bb & 0xffffffffull);
    cenx = s_cx[p][mw]; ceny = s_cy[p][mw]; cenz = s_cz[p][mw];
    p ^= 1;
  }
}

// ------------------- FPS body for stages 2-4 (LDS xyz) ---------------------
// smem layout: u64 s_pack[2][NW] | float s_x[N] | s_y[N] | s_z[N]
template <int N, int NPOINT, int T>
__device__ __forceinline__ void fps_body_lds(char* smem,
                                             const float* __restrict__ xyz,
                                             int* __restrict__ fidx, int b) {
#pragma clang fp contract(off)
  constexpr int PT = N / T;
  static_assert(PT % 2 == 0, "PT even");
  constexpr int NP2 = PT / 2;
  constexpr int NW = T / 64;
  constexpr int NACC = (NP2 >= 4) ? 4 : NP2;
  u64* s_pack = (u64*)smem;  // [2][NW]
  float* s_x = (float*)(smem + 2 * NW * sizeof(u64));
  float* s_y = s_x + N;
  float* s_z = s_y + N;
  const int t = threadIdx.x;
  const int lane = t & 63;
  const int wv = t >> 6;
  const float* base = xyz + (size_t)b * N * 3;

  v2f px[NP2], py[NP2], pz[NP2], dv[NP2];
#pragma unroll
  for (int j = 0; j < NP2; ++j) {
    int i0 = t + (2 * j) * T;
    int i1 = t + (2 * j + 1) * T;
    px[j][0] = base[i0 * 3 + 0]; py[j][0] = base[i0 * 3 + 1];
    pz[j][0] = base[i0 * 3 + 2];
    px[j][1] = base[i1 * 3 + 0]; py[j][1] = base[i1 * 3 + 1];
    pz[j][1] = base[i1 * 3 + 2];
    dv[j][0] = 1e10f; dv[j][1] = 1e10f;
    s_x[i0] = px[j][0]; s_y[i0] = py[j][0]; s_z[i0] = pz[j][0];
    s_x[i1] = px[j][1]; s_y[i1] = py[j][1]; s_z[i1] = pz[j][1];
  }
  __syncthreads();

  int far = 0;
  int p = 0;
  for (int it = 0; it < NPOINT; ++it) {
    if (t == 0) fidx[b * NPOINT + it] = far;
    float cx = s_x[far], cy = s_y[far], cz = s_z[far];
    const float nx = -cx, ny = -cy, nz = -cz;
    const v2f c2x = {nx, nx}, c2y = {ny, ny}, c2z = {nz, nz};

    float mx[NACC];
#pragma unroll
    for (int q = 0; q < NACC; ++q) mx[q] = -1.0f;

#pragma unroll
    for (int j = 0; j < NP2; ++j) {
      v2f dx = pk_add(px[j], c2x);
      v2f dy = pk_add(py[j], c2y);
      v2f dz = pk_add(pz[j], c2z);
      v2f xx = pk_mul(dx, dx);
      v2f yy = pk_mul(dy, dy);
      v2f zz = pk_mul(dz, dz);
      v2f s = pk_add(xx, yy);
      v2f d = pk_add(s, zz);
      float nd0 = fminf(dv[j][0], d[0]);
      float nd1 = fminf(dv[j][1], d[1]);
      dv[j][0] = nd0; dv[j][1] = nd1;
      const int q = j % NACC;
      mx[q] = fmaxf(fmaxf(nd0, nd1), mx[q]);
    }
    float m = mx[0];
#pragma unroll
    for (int q = 1; q < NACC; ++q) m = fmaxf(m, mx[q]);

    int bk = 0;
#pragma unroll
    for (int j = NP2 - 1; j >= 0; --j) {
      if (dv[j][1] == m) bk = 2 * j + 1;
      if (dv[j][0] == m) bk = 2 * j;
    }

    int idx = t + bk * T;
    u64 P = ((u64)__float_as_uint(m) << 32) | (unsigned)(N - idx);
    P = wave_max_u64(P);
    if (lane == 63) s_pack[p * NW + wv] = P;
    __syncthreads();
    u64 bbp = s_pack[p * NW + 0];
#pragma unroll
    for (int w = 1; w < NW; ++w) {
      u64 v = s_pack[p * NW + w];
      bbp = v > bbp ? v : bbp;
    }
    far = N - (int)(unsigned)(bbp & 0xffffffffull);
    p ^= 1;
  }
}

// --------------------------- gather new_xyz --------------------------------
__global__ void gather_xyz_kernel(const float* __restrict__ xyz,
                                  const int* __restrict__ fidx,
                                  float* __restrict__ out, int N, int S) {
  int s = blockIdx.x * blockDim.x + threadIdx.x;
  int b = blockIdx.y;
  if (s < S) {
    int i = fidx[b * S + s];
    out[((size_t)(b * S + s)) * 3 + 0] = xyz[((size_t)(b * N + i)) * 3 + 0];
    out[((size_t)(b * S + s)) * 3 + 1] = xyz[((size_t)(b * N + i)) * 3 + 1];
    out[((size_t)(b * S + s)) * 3 + 2] = xyz[((size_t)(b * N + i)) * 3 + 2];
  }
}

// ----------------------------- ball query ----------------------------------
template <int N, int NS>
__global__ __launch_bounds__(256) void ball_query_kernel(
    const float* __restrict__ xyz, const float* __restrict__ new_xyz,
    int* __restrict__ nidx, int S, float r2) {
#pragma clang fp contract(off)
  const int wv = threadIdx.x >> 6;
  const int lane = threadIdx.x & 63;
  const int b = blockIdx.y;
  const int s = blockIdx.x * 4 + wv;
  __shared__ int s_idx[4][NS];
  const float* base = xyz + (size_t)b * N * 3;

  float cx = new_xyz[((size_t)(b * S + s)) * 3 + 0];
  float cy = new_xyz[((size_t)(b * S + s)) * 3 + 1];
  float cz = new_xyz[((size_t)(b * S + s)) * 3 + 2];
  float sc = (cx * cx + cy * cy) + cz * cz;

  int found = 0;
  for (int i0 = 0; i0 < N && found < NS; i0 += 64) {
    int i = i0 + lane;
    float x = base[i * 3 + 0];
    float y = base[i * 3 + 1];
    float z = base[i * 3 + 2];
    float sx = (x * x + y * y) + z * z;
    float dt = (cx * x + cy * y) + cz * z;
    float d2 = (sc + sx) - 2.0f * dt;
    bool inb = d2 < r2;
    unsigned long long m = __ballot(inb);
    if (inb) {
      int pos = found + __popcll(m & ((1ull << lane) - 1));
      if (pos < NS) s_idx[wv][pos] = i;
    }
    found += __popcll(m);
  }
  __syncthreads();
  int fcnt = found < NS ? found : NS;
  int first = s_idx[wv][0];
  int* outp = nidx + ((size_t)(b * S + s)) * NS;
  for (int j = lane; j < NS; j += 64) outp[j] = (j < fcnt) ? s_idx[wv][j] : first;
}

// --------------------------- fused group MLP -------------------------------
template <int R, int RG, int CG, int CMAXP, int CIN, int COUT>
__device__ __forceinline__ void mlp_layer(float* act, const float* __restrict__ w,
                                          const float* __restrict__ bias, int tid) {
  constexpr int RPT = R / RG;
  constexpr int CPT = COUT / CG;
  static_assert(RG * CG == 256, "thread grid");
  const int rg = tid / CG;
  const int cg = tid % CG;

  float acc[RPT][CPT];
#pragma unroll
  for (int rr = 0; rr < RPT; ++rr)
#pragma unroll
    for (int cc = 0; cc < CPT; ++cc) acc[rr][cc] = 0.f;

  constexpr int K4 = (CIN / 4) * 4;
  for (int k = 0; k < K4; k += 4) {
    float4 a[RPT];
#pragma unroll
    for (int rr = 0; rr < RPT; ++rr)
      a[rr] = *(const float4*)(&act[(rg * RPT + rr) * CMAXP + k]);
    float wvv[4][CPT];
#pragma unroll
    for (int kk = 0; kk < 4; ++kk)
#pragma unroll
      for (int cc = 0; cc < CPT; ++cc)
        wvv[kk][cc] = w[(size_t)(k + kk) * COUT + cg + cc * CG];
#pragma unroll
    for (int rr = 0; rr < RPT; ++rr) {
      float4 av = a[rr];
#pragma unroll
      for (int cc = 0; cc < CPT; ++cc) {
        acc[rr][cc] += av.x * wvv[0][cc];
        acc[rr][cc] += av.y * wvv[1][cc];
        acc[rr][cc] += av.z * wvv[2][cc];
        acc[rr][cc] += av.w * wvv[3][cc];
      }
    }
  }
#pragma unroll 1
  for (int k = K4; k < CIN; ++k) {
    float wvv[CPT];
#pragma unroll
    for (int cc = 0; cc < CPT; ++cc) wvv[cc] = w[(size_t)k * COUT + cg + cc * CG];
#pragma unroll
    for (int rr = 0; rr < RPT; ++rr) {
      float av = act[(rg * RPT + rr) * CMAXP + k];
#pragma unroll
      for (int cc = 0; cc < CPT; ++cc) acc[rr][cc] += av * wvv[cc];
    }
  }
  __syncthreads();
#pragma unroll
  for (int rr = 0; rr < RPT; ++rr)
#pragma unroll
    for (int cc = 0; cc < CPT; ++cc) {
      int co = cg + cc * CG;
      float v = acc[rr][cc] + bias[co];
      act[(rg * RPT + rr) * CMAXP + co] = fmaxf(v, 0.f);
    }
  __syncthreads();
}

template <int NS, int G, int CPREV, int CO0, int CO1, int CO2, int RG, int CG, int CMAXP>
__device__ __forceinline__ void group_mlp_body(
    char* smem, const float* __restrict__ xyz, const float* __restrict__ new_xyz,
    const float* __restrict__ feats, const int* __restrict__ nidx,
    const float* __restrict__ w0, const float* __restrict__ b0,
    const float* __restrict__ w1, const float* __restrict__ b1,
    const float* __restrict__ w2, const float* __restrict__ b2,
    float* __restrict__ out, int N, int S, float radius, int sblk, int b) {
  constexpr int R = NS * G;
  constexpr int CIN = 3 + CPREV;
  float* act = (float*)smem;  // [R][CMAXP]
  const int tid = threadIdx.x;
  const int s0 = sblk * G;

  for (int i = tid; i < R * CIN; i += 256) {
    int row = i / CIN;
    int ch = i - row * CIN;
    int g = row / NS;
    int j = row - g * NS;
    int sidx = s0 + g;
    int n = nidx[((size_t)(b * S + sidx)) * NS + j];
    float v;
    if constexpr (CPREV == 0) {
      v = (xyz[((size_t)(b * N + n)) * 3 + ch] -
           new_xyz[((size_t)(b * S + sidx)) * 3 + ch]) /
          radius;
    } else {
      if (ch < 3) {
        v = (xyz[((size_t)(b * N + n)) * 3 + ch] -
             new_xyz[((size_t)(b * S + sidx)) * 3 + ch]) /
            radius;
      } else {
        v = feats[((size_t)(b * N + n)) * CPREV + (ch - 3)];
      }
    }
    act[row * CMAXP + ch] = v;
  }
  __syncthreads();

  mlp_layer<R, RG, CG, CMAXP, CIN, CO0>(act, w0, b0, tid);
  mlp_layer<R, RG, CG, CMAXP, CO0, CO1>(act, w1, b1, tid);
  mlp_layer<R, RG, CG, CMAXP, CO1, CO2>(act, w2, b2, tid);

  for (int i = tid; i < G * CO2; i += 256) {
    int g = i / CO2;
    int co = i - g * CO2;
    float m = act[(g * NS) * CMAXP + co];
    for (int j = 1; j < NS; ++j) m = fmaxf(m, act[(g * NS + j) * CMAXP + co]);
    out[((size_t)(b * S + s0 + g)) * CO2 + co] = m;
  }
}

// standalone MLP kernel (stage 4)
template <int NS, int G, int CPREV, int CO0, int CO1, int CO2, int RG, int CG, int CMAXP>
__global__ __launch_bounds__(256, 4) void group_mlp_kernel(
    const float* __restrict__ xyz, const float* __restrict__ new_xyz,
    const float* __restrict__ feats, const int* __restrict__ nidx,
    const float* __restrict__ w0, const float* __restrict__ b0,
    const float* __restrict__ w1, const float* __restrict__ b1,
    const float* __restrict__ w2, const float* __restrict__ b2,
    float* __restrict__ out, int N, int S, float radius) {
  __shared__ __align__(16) char smem[NS * G * CMAXP * 4];
  group_mlp_body<NS, G, CPREV, CO0, CO1, CO2, RG, CG, CMAXP>(
      smem, xyz, new_xyz, feats, nidx, w0, b0, w1, b1, w2, b2, out, N, S,
      radius, blockIdx.x, blockIdx.y);
}

// ----------------- fused: stage-(s+1) FPS || stage-s MLP -------------------
template <int FN, int FNP, int FT, int NS, int G, int CPREV, int CO0, int CO1,
          int CO2, int RG, int CG, int CMAXP>
__global__ __launch_bounds__(256, 4) void fused_fps_mlp_kernel(
    const float* __restrict__ fpts, int* __restrict__ fidx,
    const float* __restrict__ xyz, const float* __restrict__ new_xyz,
    const float* __restrict__ feats, const int* __restrict__ nidx,
    const float* __restrict__ w0, const float* __restrict__ b0,
    const float* __restrict__ w1, const float* __restrict__ b1,
    const float* __restrict__ w2, const float* __restrict__ b2,
    float* __restrict__ out, int N, int S, float radius, int SBLK) {
  constexpr int FPS_B = 2 * (FT / 64) * (int)sizeof(u64) + 3 * FN * 4;
  constexpr int MLP_B = NS * G * CMAXP * 4;
  constexpr int SB = (FPS_B > MLP_B) ? FPS_B : MLP_B;
  __shared__ __align__(16) char smem[SB];
  if ((int)blockIdx.x < B_SZ) {
    __builtin_amdgcn_s_setprio(1);  // FPS is the latency-critical path
    fps_body_lds<FN, FNP, FT>(smem, fpts, fidx, blockIdx.x);
    __builtin_amdgcn_s_setprio(0);
  } else {
    int bid = (int)blockIdx.x - B_SZ;
    group_mlp_body<NS, G, CPREV, CO0, CO1, CO2, RG, CG, CMAXP>(
        smem, xyz, new_xyz, feats, nidx, w0, b0, w1, b1, w2, b2, out, N, S,
        radius, bid % SBLK, bid / SBLK);
  }
}

// ---------------------------------------------------------------------------
extern "C" void kernel_launch(void* const* d_in, const int* in_sizes, int n_in,
                              void* d_out, int out_size, void* d_ws, size_t ws_size,
                              hipStream_t stream) {
  (void)in_sizes; (void)n_in; (void)out_size; (void)ws_size;
  const float* pc = (const float*)d_in[0];
  const float* W[4][3];
  const float* Bb[4][3];
  for (int s = 0; s < 4; ++s)
    for (int l = 0; l < 3; ++l) {
      W[s][l] = (const float*)d_in[1 + s * 6 + l * 2];
      Bb[s][l] = (const float*)d_in[2 + s * 6 + l * 2];
    }

  // workspace: fidx 32KB | nidx 2MB | xyzA 96KB | xyzB 96KB | featA 4MB | featB 4MB
  char* wsp = (char*)d_ws;
  int* fidx = (int*)wsp;
  int* nidx = (int*)(wsp + (32 << 10));
  float* xyzA = (float*)(wsp + (32 << 10) + (2 << 20));
  float* xyzB = xyzA + B_SZ * 2048 * 3;
  float* featA = xyzB + B_SZ * 2048 * 3;
  float* featB = featA + B_SZ * 2048 * 128;
  float* oxyz = (float*)d_out;           // [4,256,3]
  float* ofeat = oxyz + B_SZ * 256 * 3;  // [4,256,512]

  // ---------------- Stage 1: N=16384 -> S=2048, r=0.2, ns=64, 3->64->64->128
  hipLaunchKernelGGL((fps1_kernel<16384, 2048, 512>), dim3(B_SZ), dim3(512), 0, stream,
                     pc, fidx);
  hipLaunchKernelGGL(gather_xyz_kernel, dim3(32, B_SZ), dim3(64), 0, stream,
                     pc, fidx, xyzA, 16384, 2048);
  hipLaunchKernelGGL((ball_query_kernel<16384, 64>), dim3(512, B_SZ), dim3(256), 0, stream,
                     pc, xyzA, nidx, 2048, (float)(0.2 * 0.2));

  // ---------------- F2: stage-2 FPS (N=2048->1024) || stage-1 MLP
  hipLaunchKernelGGL((fused_fps_mlp_kernel<2048, 1024, 256,
                                           64, 1, 0, 64, 64, 128, 8, 32, 128>),
                     dim3(B_SZ + 2048 * B_SZ), dim3(256), 0, stream,
                     xyzA, fidx,
                     pc, xyzA, (const float*)nullptr, nidx,
                     W[0][0], Bb[0][0], W[0][1], Bb[0][1], W[0][2], Bb[0][2],
                     featA, 16384, 2048, 0.2f, 2048);
  hipLaunchKernelGGL(gather_xyz_kernel, dim3(16, B_SZ), dim3(64), 0, stream,
                     xyzA, fidx, xyzB, 2048, 1024);
  hipLaunchKernelGGL((ball_query_kernel<2048, 32>), dim3(256, B_SZ), dim3(256), 0, stream,
                     xyzA, xyzB, nidx, 1024, (float)(0.4 * 0.4));

  // ---------------- F3: stage-3 FPS (N=1024->512) || stage-2 MLP
  hipLaunchKernelGGL((fused_fps_mlp_kernel<1024, 512, 256,
                                           32, 1, 128, 128, 128, 256, 4, 64, 256>),
                     dim3(B_SZ + 1024 * B_SZ), dim3(256), 0, stream,
                     xyzB, fidx,
                     xyzA, xyzB, featA, nidx,
                     W[1][0], Bb[1][0], W[1][1], Bb[1][1], W[1][2], Bb[1][2],
                     featB, 2048, 1024, 0.4f, 1024);
  hipLaunchKernelGGL(gather_xyz_kernel, dim3(8, B_SZ), dim3(64), 0, stream,
                     xyzB, fidx, xyzA, 1024, 512);
  hipLaunchKernelGGL((ball_query_kernel<1024, 16>), dim3(128, B_SZ), dim3(256), 0, stream,
                     xyzB, xyzA, nidx, 512, (float)(0.6 * 0.6));

  // ---------------- F4: stage-4 FPS (N=512->256) || stage-3 MLP
  hipLaunchKernelGGL((fused_fps_mlp_kernel<512, 256, 256,
                                           16, 1, 256, 256, 256, 512, 2, 128, 512>),
                     dim3(B_SZ + 512 * B_SZ), dim3(256), 0, stream,
                     xyzA, fidx,
                     xyzB, xyzA, featB, nidx,
                     W[2][0], Bb[2][0], W[2][1], Bb[2][1], W[2][2], Bb[2][2],
                     featA, 1024, 512, 0.6f, 512);
  hipLaunchKernelGGL(gather_xyz_kernel, dim3(4, B_SZ), dim3(64), 0, stream,
                     xyzA, fidx, oxyz, 512, 256);
  hipLaunchKernelGGL((ball_query_kernel<512, 8>), dim3(64, B_SZ), dim3(256), 0, stream,
                     xyzA, oxyz, nidx, 256, (float)(1.2 * 1.2));

  // ---------------- stage-4 MLP (standalone)
  hipLaunchKernelGGL((group_mlp_kernel<8, 2, 512, 512, 512, 512, 2, 128, 516>),
                     dim3(128, B_SZ), dim3(256), 0, stream,
                     xyzA, oxyz, featA, nidx,
                     W[3][0], Bb[3][0], W[3][1], Bb[3][1], W[3][2], Bb[3][2],
                     ofeat, 512, 256, 1.2f);
}